// Round 11
// baseline (195.522 us; speedup 1.0000x reference)
//
#include <hip/hip_runtime.h>

// CTC batch loss (keras ctc_batch_cost), B=256, T=512, C=256, U=64.
// One block of 4 waves per batch (1 block/CU). Wave 0 runs the serial
// forward recurrence (lane l owns extended states 2l, 2l+1; lane 63 also
// state 128; linear domain, wave-uniform power-of-2 rescale every 8 steps
// -- numerics identical to all verified kernels, absmax 16.0).
//
// Evidence r3/r6/r7/r9/r10: every global_load_lds-based structure (1-wave,
// producer/consumer, 4-wave parallel staging) lands at 193.3-194.5 us =>
// kernel ~37us = 14 GB/s/CU -- a per-CU LDS-DMA service cap, independent
// of wave count and architected depth. UNTESTED path: plain
// global_load_dwordx4 into VGPRs (the path the 6.3 TB/s copy ubench uses).
//
// This round: 4-phase register-staged pipeline on the plain-load path.
// Iter c: [w0: asm ds_read gathers of chunk c] ; all waves issue chunk c+4
// (4 dwordx4 -> phase regs s[c&3]); counted vmcnt(12) (= chunk c+1 landed;
// never 0 in main loop); ds_write_b128 chunk c+1 -> lds ring [(c+1)&1];
// lgkm fence; s_barrier; [w0: 16 recurrence steps]. 16 loads x 1KB in
// flight per wave = 64 KB/CU.
// Hazards: VGPR WAR (GLD into sX vs prior ds_write reading sX) closed by
// the previous iteration's lgkmcnt(0) (write COMPLETED) + barrier. LDS WAR
// (writes buf (c+1)&1 vs w0 reads buf c&1) disjoint; w0's reads of the
// re-targeted buffer drained at its own fence one iteration earlier.
// All staging memops are volatile asm => compiler cannot reorder or
// insert pipeline-draining waits (rule #18 fences included).

constexpr int B = 256, T = 512, C = 256, U = 64;
constexpr int CH = 16;  // time-steps per chunk
#define EPSF 1e-7f

typedef float f4 __attribute__((ext_vector_type(4)));

#define LDSA(p) ((unsigned)(size_t)(__attribute__((address_space(3))) void*)(p))

__device__ __forceinline__ float dpp_wave_shr1(float x) {
    // alpha[2l-1]: previous lane's a_odd; lane 0 gets 0 (bound_ctrl).
    return __int_as_float(__builtin_amdgcn_update_dpp(
        0, __float_as_int(x), 0x138, 0xf, 0xf, true));
}

#define DPPMAX(ctrl)                                                      \
    {                                                                     \
        float x_ = __int_as_float(__builtin_amdgcn_update_dpp(            \
            0, __float_as_int(m_), (ctrl), 0xf, 0xf, true));              \
        m_ = fmaxf(m_, x_);                                               \
    }

#define RESCALE()                                                         \
    {                                                                     \
        float m_ = fmaxf(fmaxf(a_even, a_odd), a_top);                    \
        DPPMAX(0x111) DPPMAX(0x112) DPPMAX(0x114) DPPMAX(0x118)           \
        DPPMAX(0x142) DPPMAX(0x143)                                       \
        const float mx_ = __int_as_float(                                 \
            __builtin_amdgcn_readlane(__float_as_int(m_), 63));           \
        int e_ = (__float_as_int(mx_) >> 23) & 0xff;                      \
        int k_ = 187 - e_;                                                \
        k_ = k_ > 127 ? 127 : k_;                                         \
        const float s_ = __int_as_float((k_ + 127) << 23);                \
        a_even *= s_; a_odd *= s_; a_top *= s_;                           \
        esum += k_;                                                       \
    }

// Plain coalesced load: one dwordx4 per row per wave (64 lanes x 16B = 1KB).
#define GLD(dst, p)                                                        \
    asm volatile("global_load_dwordx4 %0, %1, off" : "=&v"(dst) : "v"(p));

// Issue this wave's 4 rows of chunk cc into phase array ST.
#define ISSUE(cc, ST)                                                      \
    {                                                                      \
        const int c_ = (cc);                                               \
        _Pragma("unroll")                                                  \
        for (int j = 0; j < 4; ++j) {                                      \
            int t = 1 + c_ * CH + rbase + j;                               \
            t = t < T ? t : T - 1;                                         \
            const float* g_ = rowp + t * C + (lane << 2);                  \
            GLD(ST[j], g_)                                                 \
        }                                                                  \
    }

// Write phase array ST (4 rows, arrived) to LDS at wave base WB.
#define WRITE4(ST, WB)                                                     \
    asm volatile("ds_write_b128 %0, %1" :: "v"(WB), "v"(ST[0]));           \
    asm volatile("ds_write_b128 %0, %1 offset:1024" :: "v"(WB), "v"(ST[1]));\
    asm volatile("ds_write_b128 %0, %1 offset:2048" :: "v"(WB), "v"(ST[2]));\
    asm volatile("ds_write_b128 %0, %1 offset:3072" :: "v"(WB), "v"(ST[3]));

#define VMC(N)                                                             \
    asm volatile("s_waitcnt vmcnt(" #N ")" ::: "memory");                  \
    __builtin_amdgcn_sched_barrier(0);

#define DSR(dst, addr, OS)                                                 \
    asm volatile("ds_read_b32 %0, %1 offset:" OS                           \
                 : "=v"(dst) : "v"(addr));

// w0: issue chunk's 32 LDS gathers (labels per-lane, blank broadcast).
#define GATHER(LA, BA)                                                     \
    {                                                                      \
        DSR(lab[0],  LA, "0")     DSR(lab[1],  LA, "1024")                 \
        DSR(lab[2],  LA, "2048")  DSR(lab[3],  LA, "3072")                 \
        DSR(lab[4],  LA, "4096")  DSR(lab[5],  LA, "5120")                 \
        DSR(lab[6],  LA, "6144")  DSR(lab[7],  LA, "7168")                 \
        DSR(lab[8],  LA, "8192")  DSR(lab[9],  LA, "9216")                 \
        DSR(lab[10], LA, "10240") DSR(lab[11], LA, "11264")                \
        DSR(lab[12], LA, "12288") DSR(lab[13], LA, "13312")                \
        DSR(lab[14], LA, "14336") DSR(lab[15], LA, "15360")                \
        DSR(blk[0],  BA, "0")     DSR(blk[1],  BA, "1024")                 \
        DSR(blk[2],  BA, "2048")  DSR(blk[3],  BA, "3072")                 \
        DSR(blk[4],  BA, "4096")  DSR(blk[5],  BA, "5120")                 \
        DSR(blk[6],  BA, "6144")  DSR(blk[7],  BA, "7168")                 \
        DSR(blk[8],  BA, "8192")  DSR(blk[9],  BA, "9216")                 \
        DSR(blk[10], BA, "10240") DSR(blk[11], BA, "11264")                \
        DSR(blk[12], BA, "12288") DSR(blk[13], BA, "13312")                \
        DSR(blk[14], BA, "14336") DSR(blk[15], BA, "15360")                \
    }

#define FENCE_BAR()                                                        \
    asm volatile("s_waitcnt lgkmcnt(0)" ::: "memory");                     \
    __builtin_amdgcn_sched_barrier(0);                                     \
    __builtin_amdgcn_s_barrier();

// NSTEPS recurrence steps. t = 1 + cc*CH + i; (t & 7) == 0 iff
// ((1 + i) & 7) == 0 (CH multiple of 8) -- compile-time cadence.
#define COMP_CHUNK(NSTEPS)                                                 \
    {                                                                      \
        _Pragma("unroll")                                                  \
        for (int i = 0; i < (NSTEPS); ++i) {                               \
            const float pb = blk[i] + EPSF;                                \
            const float pl = lab[i] + EPSF;                                \
            const float po = dpp_wave_shr1(a_odd);                         \
            const float skp = skip_ok ? po : 0.f;                          \
            const float ne = (a_even + po) * pb;                           \
            const float no = (a_odd + a_even + skp) * pl;                  \
            const float nt = (a_top + a_odd) * pb;                         \
            a_even = ne; a_odd = no; a_top = nt;                           \
            if (((1 + i) & 7) == 0) RESCALE();                             \
        }                                                                  \
    }

// One steady-state iteration. STI: issue phase (c&3); STW: write phase
// ((c+1)&3); WB: write base buf (c+1)&1; LA/BA: gather addrs buf c&1.
#define ITER(cc, STI, STW, WB, LA, BA)                                     \
    {                                                                      \
        if (wid == 0) { GATHER(LA, BA) }                                   \
        __builtin_amdgcn_sched_barrier(0);                                 \
        ISSUE((cc) + 4, STI)                                               \
        VMC(12)                                                            \
        WRITE4(STW, WB)                                                    \
        FENCE_BAR()                                                        \
        if (wid == 0) { COMP_CHUNK(CH) }                                   \
    }

// Tail iteration: no new issue; NN = counted wait for chunk cc+1.
#define ITER_T(cc, NN, STW, WB, LA, BA)                                    \
    {                                                                      \
        if (wid == 0) { GATHER(LA, BA) }                                   \
        __builtin_amdgcn_sched_barrier(0);                                 \
        VMC(NN)                                                            \
        WRITE4(STW, WB)                                                    \
        FENCE_BAR()                                                        \
        if (wid == 0) { COMP_CHUNK(CH) }                                   \
    }

__global__ __launch_bounds__(256) void ctc_kernel(const int* __restrict__ y_true,
                                                  const float* __restrict__ y_pred,
                                                  float* __restrict__ out) {
    __shared__ float rows[2][CH][C];  // 2 x 16 x 1KB = 32 KB ring
    const int b = blockIdx.x;
    const int tid = threadIdx.x;
    const int lane = tid & 63;
    const int wid = tid >> 6;
    const int rbase = wid << 2;  // this wave's 4 rows of each chunk
    const float* __restrict__ rowp = y_pred + (size_t)b * (T * C);

    const int label = y_true[b * U + lane];
    const int label_prev = __shfl_up(label, 1);
    const bool skip_ok = (lane > 0) && (label != label_prev);

    float a_even = 0.f, a_odd = 0.f, a_top = 0.f;
    int esum = 0;  // stored = true * 2^esum
    float lab[CH], blk[CH];

    if (wid == 0) {
        // t = 0 init (linear domain; unreachable states = 0).
        const float pb = rowp[C - 1] + EPSF;
        const float pl = rowp[label] + EPSF;
        a_even = (lane == 0) ? pb : 0.f;
        a_odd  = (lane == 0) ? pl : 0.f;
    }

    // LDS addresses (per-wave write bases; per-lane gather bases).
    const unsigned wb0 = LDSA(&rows[0][rbase][0]) + (lane << 4);
    const unsigned wb1 = LDSA(&rows[1][rbase][0]) + (lane << 4);
    const unsigned labA0 = LDSA(&rows[0][0][label]);
    const unsigned labA1 = LDSA(&rows[1][0][label]);
    const unsigned blkA0 = LDSA(&rows[0][0][C - 1]);
    const unsigned blkA1 = LDSA(&rows[1][0][C - 1]);

    f4 s0[4], s1[4], s2[4], s3[4];

    // Drain init loads so asm vmcnt bookkeeping is exact on all waves.
    asm volatile("s_waitcnt vmcnt(0)" ::: "memory");
    __builtin_amdgcn_sched_barrier(0);

    // Prologue: issue chunks 0..3 (16 loads = 16 KB in flight per wave),
    // land chunk 0, publish it in buf 0.
    ISSUE(0, s0) ISSUE(1, s1) ISSUE(2, s2) ISSUE(3, s3)
    VMC(12)
    WRITE4(s0, wb0)
    FENCE_BAR()

    // Main loop c = 0..27 (7 x 4 phases, all register indices literal).
    for (int q = 0; q < 7; ++q) {
        const int c = q << 2;
        ITER(c + 0, s0, s1, wb1, labA0, blkA0)
        ITER(c + 1, s1, s2, wb0, labA1, blkA1)
        ITER(c + 2, s2, s3, wb1, labA0, blkA0)
        ITER(c + 3, s3, s0, wb0, labA1, blkA1)
    }
    // Tail: c = 28, 29, 30 (outstanding 12 -> 8 -> 4 -> 0).
    ITER_T(28, 8, s1, wb1, labA0, blkA0)
    ITER_T(29, 4, s2, wb0, labA1, blkA1)
    ITER_T(30, 0, s3, wb1, labA0, blkA0)

    // c = 31: consumer only; t = 497..511 -> 15 steps.
    if (wid == 0) {
        GATHER(labA1, blkA1)
        asm volatile("s_waitcnt lgkmcnt(0)" ::: "memory");
        __builtin_amdgcn_sched_barrier(0);
        COMP_CHUNK(CH - 1)
        // loss = -ln(alpha[128] + alpha[127]); true = stored * 2^-esum
        if (lane == 63)
            out[b] = -logf(a_top + a_odd) + (float)esum * 0.69314718055994531f;
    }
}

extern "C" void kernel_launch(void* const* d_in, const int* in_sizes, int n_in,
                              void* d_out, int out_size, void* d_ws, size_t ws_size,
                              hipStream_t stream) {
    const int* y_true   = (const int*)d_in[0];
    const float* y_pred = (const float*)d_in[1];
    float* out = (float*)d_out;
    hipLaunchKernelGGL(ctc_kernel, dim3(B), dim3(256), 0, stream,
                       y_true, y_pred, out);
}